// Round 1
// baseline (155.704 us; speedup 1.0000x reference)
//
#include <hip/hip_runtime.h>

#define NX 192
#define NY 192
#define NZ 192
#define NB 2

constexpr int ZPT = 4;            // z voxels per thread
constexpr int BY  = 8;            // y rows per block
constexpr int TZ  = NZ / ZPT;     // 48 z-chunks = blockDim.x
constexpr int BLOCK_THREADS = TZ * BY;   // 384 = 6 waves

__global__ __launch_bounds__(BLOCK_THREADS)
void ncc_partial(const float* __restrict__ pred,
                 const float* __restrict__ label,
                 float* __restrict__ partials) {
    const int tx = threadIdx.x;            // z-chunk index
    const int ty = threadIdx.y;            // y within tile
    const int z0 = tx * ZPT;
    const int y  = blockIdx.x * BY + ty;
    const int x  = blockIdx.y;
    const int b  = blockIdx.z;

    // Per-z-plane sums over the 3x3 xy neighborhood, for z0-1 .. z0+ZPT
    float Pt[ZPT + 2]  = {0, 0, 0, 0, 0, 0};
    float Pp[ZPT + 2]  = {0, 0, 0, 0, 0, 0};
    float Pt2[ZPT + 2] = {0, 0, 0, 0, 0, 0};
    float Pp2[ZPT + 2] = {0, 0, 0, 0, 0, 0};
    float Ptp[ZPT + 2] = {0, 0, 0, 0, 0, 0};

    const size_t plane = (size_t)NY * NZ;
    const size_t bbase = (size_t)b * NX * plane;

    #pragma unroll
    for (int dx = -1; dx <= 1; ++dx) {
        const int xx = x + dx;
        if ((unsigned)xx >= NX) continue;
        #pragma unroll
        for (int dy = -1; dy <= 1; ++dy) {
            const int yy = y + dy;
            if ((unsigned)yy >= NY) continue;
            const size_t base = bbase + (size_t)xx * plane + (size_t)yy * NZ + z0;
            // aligned 16B load covering z0..z0+3 (row start is 768B-aligned, z0 % 4 == 0)
            const float4 t4 = *reinterpret_cast<const float4*>(label + base);
            const float4 p4 = *reinterpret_cast<const float4*>(pred + base);
            const float tm = (z0 > 0)        ? label[base - 1]   : 0.f;
            const float pm = (z0 > 0)        ? pred[base - 1]    : 0.f;
            const float te = (z0 + ZPT < NZ) ? label[base + ZPT] : 0.f;
            const float pe = (z0 + ZPT < NZ) ? pred[base + ZPT]  : 0.f;

            const float tv[ZPT + 2] = {tm, t4.x, t4.y, t4.z, t4.w, te};
            const float pv[ZPT + 2] = {pm, p4.x, p4.y, p4.z, p4.w, pe};
            #pragma unroll
            for (int j = 0; j < ZPT + 2; ++j) {
                Pt[j]  += tv[j];
                Pp[j]  += pv[j];
                Pt2[j] = fmaf(tv[j], tv[j], Pt2[j]);
                Pp2[j] = fmaf(pv[j], pv[j], Pp2[j]);
                Ptp[j] = fmaf(tv[j], pv[j], Ptp[j]);
            }
        }
    }

    // z-window sum (3-tap) + NCC epilogue, accumulate locally
    float acc = 0.f;
    const float inv_vol = 1.0f / 27.0f;
    #pragma unroll
    for (int zz = 0; zz < ZPT; ++zz) {
        const float st  = Pt[zz]  + Pt[zz + 1]  + Pt[zz + 2];
        const float sp  = Pp[zz]  + Pp[zz + 1]  + Pp[zz + 2];
        const float st2 = Pt2[zz] + Pt2[zz + 1] + Pt2[zz + 2];
        const float sp2 = Pp2[zz] + Pp2[zz + 1] + Pp2[zz + 2];
        const float stp = Ptp[zz] + Ptp[zz + 1] + Ptp[zz + 2];

        const float tavg = st * inv_vol;
        const float pavg = sp * inv_vol;
        const float cross = stp - pavg * st;
        const float tvar  = fmaxf(st2 - tavg * st, 0.f);
        const float pvar  = fmaxf(sp2 - pavg * sp, 0.f);
        acc += (cross * cross) / (tvar * pvar + 1e-5f);
    }

    // wave (64-lane) reduction
    #pragma unroll
    for (int off = 32; off > 0; off >>= 1)
        acc += __shfl_down(acc, off, 64);

    __shared__ float wsum[BLOCK_THREADS / 64];
    const int tid  = threadIdx.x + threadIdx.y * TZ;
    const int lane = tid & 63;
    const int wid  = tid >> 6;
    if (lane == 0) wsum[wid] = acc;
    __syncthreads();
    if (tid == 0) {
        float s = 0.f;
        #pragma unroll
        for (int w = 0; w < BLOCK_THREADS / 64; ++w) s += wsum[w];
        const int blockId = blockIdx.x + (int)gridDim.x * (blockIdx.y + (int)gridDim.y * blockIdx.z);
        partials[blockId] = s;
    }
}

__global__ __launch_bounds__(256)
void ncc_reduce(const float* __restrict__ partials, int n, float* __restrict__ out) {
    __shared__ double sh[256];
    double s = 0.0;
    for (int i = threadIdx.x; i < n; i += 256) s += (double)partials[i];
    sh[threadIdx.x] = s;
    __syncthreads();
    for (int off = 128; off > 0; off >>= 1) {
        if ((int)threadIdx.x < off) sh[threadIdx.x] += sh[threadIdx.x + off];
        __syncthreads();
    }
    if (threadIdx.x == 0) {
        const double nvox = (double)NB * NX * NY * NZ;
        out[0] = (float)(-sh[0] / nvox);
    }
}

extern "C" void kernel_launch(void* const* d_in, const int* in_sizes, int n_in,
                              void* d_out, int out_size, void* d_ws, size_t ws_size,
                              hipStream_t stream) {
    const float* pred  = (const float*)d_in[0];
    const float* label = (const float*)d_in[1];
    float* out = (float*)d_out;
    float* partials = (float*)d_ws;

    dim3 block(TZ, BY, 1);
    dim3 grid(NY / BY, NX, NB);   // 24 x 192 x 2 = 9216 blocks
    const int nblocks = (NY / BY) * NX * NB;

    ncc_partial<<<grid, block, 0, stream>>>(pred, label, partials);
    ncc_reduce<<<1, 256, 0, stream>>>(partials, nblocks, out);
}

// Round 2
// 72.349 us; speedup vs baseline: 2.1521x; 2.1521x over previous
//
#include <hip/hip_runtime.h>

constexpr int NX = 192, NY = 192, NZ = 192, NB = 2;
constexpr int ZPT  = 4;           // z outputs per thread
constexpr int TZ   = NZ / ZPT;    // 48
constexpr int BY   = 4;           // y rows per block
constexpr int XSEG = 8;           // x outputs per thread
constexpr int BLOCK_THREADS = TZ * BY;               // 192 = 3 waves
constexpr int NBLK = (NY / BY) * (NX / XSEG) * NB;   // 48*24*2 = 2304

// Compute W[q][zz] = per-(x-plane) sums over the 3x3 (y,z) window footprint:
//   for quantity q in {t, p, t^2, p^2, t*p}, summed over 3 y-rows and 3-tap z.
__device__ __forceinline__ void computeW(
    const float* __restrict__ pred, const float* __restrict__ label,
    int xx, const int rowoff[3], const bool yok[3], bool zc0, bool zcL,
    float W[5][ZPT])
{
    const bool xok = (unsigned)xx < (unsigned)NX;
    const int  xcl = min(max(xx, 0), NX - 1);
    const int  xoff = xcl * (NY * NZ);

    float S[5][ZPT + 2];
    #pragma unroll
    for (int r = 0; r < 3; ++r) {
        const bool ok  = xok && yok[r];
        const int  off = xoff + rowoff[r];
        const float4 t4 = *reinterpret_cast<const float4*>(label + off);
        const float4 p4 = *reinterpret_cast<const float4*>(pred + off);
        const int offm = off - (zc0 ? 0 : 1);
        const int offe = off + (zcL ? 0 : ZPT);
        const float tmr = label[offm], ter = label[offe];
        const float pmr = pred[offm],  per_ = pred[offe];

        const float tv[ZPT + 2] = {
            (ok && !zc0) ? tmr : 0.f,
            ok ? t4.x : 0.f, ok ? t4.y : 0.f, ok ? t4.z : 0.f, ok ? t4.w : 0.f,
            (ok && !zcL) ? ter : 0.f };
        const float pv[ZPT + 2] = {
            (ok && !zc0) ? pmr : 0.f,
            ok ? p4.x : 0.f, ok ? p4.y : 0.f, ok ? p4.z : 0.f, ok ? p4.w : 0.f,
            (ok && !zcL) ? per_ : 0.f };

        #pragma unroll
        for (int j = 0; j < ZPT + 2; ++j) {
            if (r == 0) {
                S[0][j] = tv[j];
                S[1][j] = pv[j];
                S[2][j] = tv[j] * tv[j];
                S[3][j] = pv[j] * pv[j];
                S[4][j] = tv[j] * pv[j];
            } else {
                S[0][j] += tv[j];
                S[1][j] += pv[j];
                S[2][j] = fmaf(tv[j], tv[j], S[2][j]);
                S[3][j] = fmaf(pv[j], pv[j], S[3][j]);
                S[4][j] = fmaf(tv[j], pv[j], S[4][j]);
            }
        }
    }
    #pragma unroll
    for (int q = 0; q < 5; ++q)
        #pragma unroll
        for (int zz = 0; zz < ZPT; ++zz)
            W[q][zz] = S[q][zz] + S[q][zz + 1] + S[q][zz + 2];
}

__device__ __forceinline__ float epilogue4(const float P[5][ZPT], const float Wn[5][ZPT])
{
    constexpr float inv_vol = 1.0f / 27.0f;
    float acc = 0.f;
    #pragma unroll
    for (int zz = 0; zz < ZPT; ++zz) {
        const float st  = P[0][zz] + Wn[0][zz];
        const float sp  = P[1][zz] + Wn[1][zz];
        const float st2 = P[2][zz] + Wn[2][zz];
        const float sp2 = P[3][zz] + Wn[3][zz];
        const float stp = P[4][zz] + Wn[4][zz];
        const float tavg = st * inv_vol;
        const float pavg = sp * inv_vol;
        const float cross = fmaf(-pavg, st, stp);
        const float tvar  = fmaxf(fmaf(-tavg, st, st2), 0.f);
        const float pvar  = fmaxf(fmaf(-pavg, sp, sp2), 0.f);
        acc += cross * cross * __builtin_amdgcn_rcpf(fmaf(tvar, pvar, 1e-5f));
    }
    return acc;
}

__global__ __launch_bounds__(BLOCK_THREADS, 2)
void ncc_partial(const float* __restrict__ pred, const float* __restrict__ label,
                 float* __restrict__ partials)
{
    const int zc  = threadIdx.x;
    const int ty  = threadIdx.y;
    const int z0  = zc * ZPT;
    const int y   = blockIdx.x * BY + ty;
    const int xs0 = blockIdx.y * XSEG;
    const int b   = blockIdx.z;

    bool yok[3];
    int  rowoff[3];
    #pragma unroll
    for (int r = 0; r < 3; ++r) {
        const int yy = y + r - 1;
        yok[r] = (unsigned)yy < (unsigned)NY;
        const int yycl = min(max(yy, 0), NY - 1);
        rowoff[r] = b * (NX * NY * NZ) + yycl * NZ + z0;
    }
    const bool zc0 = (zc == 0), zcL = (zc == TZ - 1);

    float U[5][ZPT], V[5][ZPT], P[5][ZPT];
    // prologue: planes xs0-1 -> U, xs0 -> V ; P = U + V
    computeW(pred, label, xs0 - 1, rowoff, yok, zc0, zcL, U);
    computeW(pred, label, xs0,     rowoff, yok, zc0, zcL, V);
    #pragma unroll
    for (int q = 0; q < 5; ++q)
        #pragma unroll
        for (int zz = 0; zz < ZPT; ++zz)
            P[q][zz] = U[q][zz] + V[q][zz];

    float acc = 0.f;
    #pragma unroll 1
    for (int k = 0; k < XSEG / 2; ++k) {
        // even step: plane xs0+1+2k -> U ; out(xs0+2k) = P + U ; P = V + U
        computeW(pred, label, xs0 + 1 + 2 * k, rowoff, yok, zc0, zcL, U);
        acc += epilogue4(P, U);
        #pragma unroll
        for (int q = 0; q < 5; ++q)
            #pragma unroll
            for (int zz = 0; zz < ZPT; ++zz)
                P[q][zz] = V[q][zz] + U[q][zz];

        // odd step: plane xs0+2+2k -> V ; out(xs0+1+2k) = P + V ; P = U + V
        computeW(pred, label, xs0 + 2 + 2 * k, rowoff, yok, zc0, zcL, V);
        acc += epilogue4(P, V);
        #pragma unroll
        for (int q = 0; q < 5; ++q)
            #pragma unroll
            for (int zz = 0; zz < ZPT; ++zz)
                P[q][zz] = U[q][zz] + V[q][zz];
    }

    // wave (64) reduction, then block sum
    #pragma unroll
    for (int o = 32; o > 0; o >>= 1)
        acc += __shfl_down(acc, o, 64);

    __shared__ float wsum[BLOCK_THREADS / 64];
    const int tid = threadIdx.x + threadIdx.y * TZ;
    if ((tid & 63) == 0) wsum[tid >> 6] = acc;
    __syncthreads();
    if (tid == 0) {
        float s = 0.f;
        #pragma unroll
        for (int w = 0; w < BLOCK_THREADS / 64; ++w) s += wsum[w];
        partials[blockIdx.x + (int)gridDim.x * (blockIdx.y + (int)gridDim.y * blockIdx.z)] = s;
    }
}

__global__ __launch_bounds__(256)
void ncc_reduce(const float* __restrict__ partials, int n, float* __restrict__ out)
{
    __shared__ double sh[256];
    double s = 0.0;
    for (int i = threadIdx.x; i < n; i += 256) s += (double)partials[i];
    sh[threadIdx.x] = s;
    __syncthreads();
    for (int off = 128; off > 0; off >>= 1) {
        if ((int)threadIdx.x < off) sh[threadIdx.x] += sh[threadIdx.x + off];
        __syncthreads();
    }
    if (threadIdx.x == 0) {
        const double nvox = (double)NB * NX * NY * NZ;
        out[0] = (float)(-sh[0] / nvox);
    }
}

extern "C" void kernel_launch(void* const* d_in, const int* in_sizes, int n_in,
                              void* d_out, int out_size, void* d_ws, size_t ws_size,
                              hipStream_t stream) {
    const float* pred  = (const float*)d_in[0];
    const float* label = (const float*)d_in[1];
    float* out = (float*)d_out;
    float* partials = (float*)d_ws;

    dim3 block(TZ, BY, 1);                 // 48 x 4 = 192 threads
    dim3 grid(NY / BY, NX / XSEG, NB);     // 48 x 24 x 2 = 2304 blocks

    ncc_partial<<<grid, block, 0, stream>>>(pred, label, partials);
    ncc_reduce<<<1, 256, 0, stream>>>(partials, NBLK, out);
}

// Round 3
// 69.917 us; speedup vs baseline: 2.2270x; 1.0348x over previous
//
#include <hip/hip_runtime.h>

constexpr int NX = 192, NY = 192, NZ = 192, NB = 2;
constexpr int ZPT  = 4;           // z outputs per thread
constexpr int TZ   = NZ / ZPT;    // 48
constexpr int BY   = 4;           // y rows per block
constexpr int XSEG = 8;           // x outputs per thread
constexpr int BLOCK_THREADS = TZ * BY;               // 192 = 3 waves
constexpr int NBLK = (NY / BY) * (NX / XSEG) * NB;   // 2304 blocks

struct RawPlane {
    float t[3][6];   // label: rows r=0..2, z elements z0-1 .. z0+4
    float p[3][6];   // pred
};

// Pure load stage: no VALU beyond addressing. Clamped addresses; zeroing is
// done in foldPlane via {0,1} weights (exact for all 5 product quantities).
__device__ __forceinline__ void loadPlane(const float* __restrict__ pred,
                                          const float* __restrict__ label,
                                          int xx, const int rowoff[3],
                                          int dm, int de, RawPlane& R)
{
    const int xcl  = min(max(xx, 0), NX - 1);
    const int xoff = xcl * (NY * NZ);
    #pragma unroll
    for (int r = 0; r < 3; ++r) {
        const int off = xoff + rowoff[r];
        const float4 t4 = *reinterpret_cast<const float4*>(label + off);
        const float4 p4 = *reinterpret_cast<const float4*>(pred + off);
        R.t[r][0] = label[off - dm];  R.p[r][0] = pred[off - dm];
        R.t[r][1] = t4.x; R.t[r][2] = t4.y; R.t[r][3] = t4.z; R.t[r][4] = t4.w;
        R.p[r][1] = p4.x; R.p[r][2] = p4.y; R.p[r][3] = p4.z; R.p[r][4] = p4.w;
        R.t[r][5] = label[off + de];  R.p[r][5] = pred[off + de];
    }
}

// Pure VALU stage: weight, products, y-fold (fused), z-fold.
__device__ __forceinline__ void foldPlane(const RawPlane& R, int xx,
                                          const float wy[3], float wzm, float wze,
                                          float W[5][ZPT])
{
    const float wx = ((unsigned)xx < (unsigned)NX) ? 1.f : 0.f;
    float S[5][6];
    #pragma unroll
    for (int r = 0; r < 3; ++r) {
        const float wr = wx * wy[r];
        const float wm = wr * wzm;
        const float we = wr * wze;
        #pragma unroll
        for (int j = 0; j < 6; ++j) {
            const float wj = (j == 0) ? wm : ((j == 5) ? we : wr);
            const float t  = R.t[r][j];
            const float p  = R.p[r][j];
            const float tw = t * wj;       // w * t   (w in {0,1} => exact)
            const float pw = p * wj;       // w * p
            if (r == 0) {
                S[0][j] = tw;
                S[1][j] = pw;
                S[2][j] = tw * t;          // w * t^2
                S[3][j] = pw * p;          // w * p^2
                S[4][j] = tw * p;          // w * t*p
            } else {
                S[0][j] += tw;
                S[1][j] += pw;
                S[2][j] = fmaf(tw, t, S[2][j]);
                S[3][j] = fmaf(pw, p, S[3][j]);
                S[4][j] = fmaf(tw, p, S[4][j]);
            }
        }
    }
    #pragma unroll
    for (int q = 0; q < 5; ++q)
        #pragma unroll
        for (int zz = 0; zz < ZPT; ++zz)
            W[q][zz] = S[q][zz] + S[q][zz + 1] + S[q][zz + 2];
}

__device__ __forceinline__ float epilogue4(const float P[5][ZPT], const float Wn[5][ZPT])
{
    constexpr float inv_vol = 1.0f / 27.0f;
    float acc = 0.f;
    #pragma unroll
    for (int zz = 0; zz < ZPT; ++zz) {
        const float st  = P[0][zz] + Wn[0][zz];
        const float sp  = P[1][zz] + Wn[1][zz];
        const float st2 = P[2][zz] + Wn[2][zz];
        const float sp2 = P[3][zz] + Wn[3][zz];
        const float stp = P[4][zz] + Wn[4][zz];
        const float tavg = st * inv_vol;
        const float pavg = sp * inv_vol;
        const float cross = fmaf(-pavg, st, stp);
        const float tvar  = fmaxf(fmaf(-tavg, st, st2), 0.f);
        const float pvar  = fmaxf(fmaf(-pavg, sp, sp2), 0.f);
        acc += cross * cross * __builtin_amdgcn_rcpf(fmaf(tvar, pvar, 1e-5f));
    }
    return acc;
}

__global__ __launch_bounds__(BLOCK_THREADS, 3)
void ncc_partial(const float* __restrict__ pred, const float* __restrict__ label,
                 float* __restrict__ partials)
{
    const int zc  = threadIdx.x;
    const int ty  = threadIdx.y;
    const int z0  = zc * ZPT;
    const int y   = blockIdx.x * BY + ty;
    const int xs0 = blockIdx.y * XSEG;
    const int b   = blockIdx.z;

    float wy[3];
    int   rowoff[3];
    #pragma unroll
    for (int r = 0; r < 3; ++r) {
        const int yy = y + r - 1;
        wy[r] = ((unsigned)yy < (unsigned)NY) ? 1.f : 0.f;
        const int yycl = min(max(yy, 0), NY - 1);
        rowoff[r] = b * (NX * NY * NZ) + yycl * NZ + z0;
    }
    const int   dm  = (zc == 0) ? 0 : 1;
    const int   de  = (zc == TZ - 1) ? 0 : ZPT;
    const float wzm = (zc == 0) ? 0.f : 1.f;
    const float wze = (zc == TZ - 1) ? 0.f : 1.f;

    RawPlane RA, RB;
    float U[5][ZPT], V[5][ZPT], P[5][ZPT];

    // ---- software-pipelined prologue ----
    loadPlane(pred, label, xs0 - 1, rowoff, dm, de, RA);
    loadPlane(pred, label, xs0,     rowoff, dm, de, RB);
    foldPlane(RA, xs0 - 1, wy, wzm, wze, U);          // W(x-1), RB in flight
    loadPlane(pred, label, xs0 + 1, rowoff, dm, de, RA);
    foldPlane(RB, xs0,     wy, wzm, wze, V);          // W(x),   RA in flight
    #pragma unroll
    for (int q = 0; q < 5; ++q)
        #pragma unroll
        for (int zz = 0; zz < ZPT; ++zz)
            P[q][zz] = U[q][zz] + V[q][zz];

    float acc = 0.f;

    // step s: (opt) issue loads of plane xs0+s+2 into BUF_LD, fold plane
    // xs0+s+1 from BUF_FD into WDST, emit output xs0+s, update P = WOTH+WDST.
#define NCC_STEP(S, BUF_FD, BUF_LD, WDST, WOTH, DOLOAD)                         \
    do {                                                                        \
        if (DOLOAD) loadPlane(pred, label, xs0 + (S) + 2, rowoff, dm, de, BUF_LD); \
        foldPlane(BUF_FD, xs0 + (S) + 1, wy, wzm, wze, WDST);                   \
        acc += epilogue4(P, WDST);                                              \
        _Pragma("unroll")                                                       \
        for (int q = 0; q < 5; ++q)                                             \
            _Pragma("unroll")                                                   \
            for (int zz = 0; zz < ZPT; ++zz)                                    \
                P[q][zz] = WOTH[q][zz] + WDST[q][zz];                           \
    } while (0)

    NCC_STEP(0, RA, RB, U, V, true);
    NCC_STEP(1, RB, RA, V, U, true);
    NCC_STEP(2, RA, RB, U, V, true);
    NCC_STEP(3, RB, RA, V, U, true);
    NCC_STEP(4, RA, RB, U, V, true);
    NCC_STEP(5, RB, RA, V, U, true);
    NCC_STEP(6, RA, RB, U, V, true);
    NCC_STEP(7, RB, RA, V, U, false);   // last fold, nothing left to load
#undef NCC_STEP

    // wave (64) reduction, then block sum
    #pragma unroll
    for (int o = 32; o > 0; o >>= 1)
        acc += __shfl_down(acc, o, 64);

    __shared__ float wsum[BLOCK_THREADS / 64];
    const int tid = threadIdx.x + threadIdx.y * TZ;
    if ((tid & 63) == 0) wsum[tid >> 6] = acc;
    __syncthreads();
    if (tid == 0) {
        float s = 0.f;
        #pragma unroll
        for (int w = 0; w < BLOCK_THREADS / 64; ++w) s += wsum[w];
        partials[blockIdx.x + (int)gridDim.x * (blockIdx.y + (int)gridDim.y * blockIdx.z)] = s;
    }
}

__global__ __launch_bounds__(256)
void ncc_reduce(const float* __restrict__ partials, int n, float* __restrict__ out)
{
    __shared__ double sh[256];
    double s = 0.0;
    for (int i = threadIdx.x; i < n; i += 256) s += (double)partials[i];
    sh[threadIdx.x] = s;
    __syncthreads();
    for (int off = 128; off > 0; off >>= 1) {
        if ((int)threadIdx.x < off) sh[threadIdx.x] += sh[threadIdx.x + off];
        __syncthreads();
    }
    if (threadIdx.x == 0) {
        const double nvox = (double)NB * NX * NY * NZ;
        out[0] = (float)(-sh[0] / nvox);
    }
}

extern "C" void kernel_launch(void* const* d_in, const int* in_sizes, int n_in,
                              void* d_out, int out_size, void* d_ws, size_t ws_size,
                              hipStream_t stream) {
    const float* pred  = (const float*)d_in[0];
    const float* label = (const float*)d_in[1];
    float* out = (float*)d_out;
    float* partials = (float*)d_ws;

    dim3 block(TZ, BY, 1);                 // 48 x 4 = 192 threads
    dim3 grid(NY / BY, NX / XSEG, NB);     // 48 x 24 x 2 = 2304 blocks

    ncc_partial<<<grid, block, 0, stream>>>(pred, label, partials);
    ncc_reduce<<<1, 256, 0, stream>>>(partials, NBLK, out);
}